// Round 2
// baseline (342.293 us; speedup 1.0000x reference)
//
#include <hip/hip_runtime.h>

// Conv2d: x [3, 2048, 2048] f32, kernel [16, 3, 3, 3] f32, pad=1, stride=1
// out [16, 2048, 2048] f32.
// Roofline: 268 MB write + ~100 MB read => ~58 us @ 6.3 TB/s; VALU fma floor 23 us.
// R1: split OC into 2 halves of 8 -> acc 32 VGPR, __launch_bounds__(256,8)
//     caps VGPR<=64 -> 8 waves/SIMD (was ~4). h from blockIdx -> scalar addr math.

#define CONV_H 2048
#define CONV_W 2048
#define CONV_IC 3
#define CONV_OC 16

// Transpose weights [oc][ic][kh][kw] -> [tap][oc], tap = ic*9+kh*3+kw.
// 16 OC weights per tap contiguous -> s_load_dwordx8 per oc-half.
__global__ void conv_weight_transpose(const float* __restrict__ k,
                                      float* __restrict__ wt) {
    int t = threadIdx.x;
    if (t < CONV_OC * CONV_IC * 9) {
        int oc = t / 27;
        int r  = t % 27;
        wt[r * CONV_OC + oc] = k[t];
    }
}

// blockIdx.x encoding: bit0 = w-half (0/1), bits1..11 = h, bit12 = oc-half.
// Each thread: 4 consecutive outputs (float4) x 8 OCs.
__global__ __launch_bounds__(256, 8) void conv2d_main(const float* __restrict__ x,
                                                      const float* __restrict__ wt,
                                                      float* __restrict__ out) {
    const int b    = blockIdx.x;
    const int ocH  = b >> 12;                 // 0 or 1
    const int h    = (b >> 1) & (CONV_H - 1); // wave-uniform, scalar math
    const int half = b & 1;
    const int w0   = (half * 256 + threadIdx.x) << 2;

    float acc[8][4];
#pragma unroll
    for (int oc = 0; oc < 8; ++oc)
#pragma unroll
        for (int j = 0; j < 4; ++j) acc[oc][j] = 0.f;

    const float* wbase = wt + ocH * 8;

#pragma unroll
    for (int ic = 0; ic < CONV_IC; ++ic) {
        const float* plane = x + (size_t)ic * CONV_H * CONV_W;
#pragma unroll
        for (int kh = 0; kh < 3; ++kh) {
            const int hy = h + kh - 1;          // wave-uniform condition
            if (hy >= 0 && hy < CONV_H) {
                const float* row = plane + (size_t)hy * CONV_W;
                const float4 c = *reinterpret_cast<const float4*>(row + w0);
                float in[6];
                in[0] = (w0 > 0) ? row[w0 - 1] : 0.f;
                in[1] = c.x; in[2] = c.y; in[3] = c.z; in[4] = c.w;
                in[5] = (w0 + 4 < CONV_W) ? row[w0 + 4] : 0.f;
#pragma unroll
                for (int kw = 0; kw < 3; ++kw) {
                    const float* wp = wbase + ((ic * 3 + kh) * 3 + kw) * CONV_OC;
#pragma unroll
                    for (int oc = 0; oc < 8; ++oc) {
                        const float wv = wp[oc];
#pragma unroll
                        for (int j = 0; j < 4; ++j)
                            acc[oc][j] = fmaf(in[kw + j], wv, acc[oc][j]);
                    }
                }
            }
        }
    }

    float* obase = out + ((size_t)ocH * 8) * CONV_H * CONV_W + (size_t)h * CONV_W + w0;
#pragma unroll
    for (int oc = 0; oc < 8; ++oc) {
        *reinterpret_cast<float4*>(obase + (size_t)oc * CONV_H * CONV_W) =
            make_float4(acc[oc][0], acc[oc][1], acc[oc][2], acc[oc][3]);
    }
}

extern "C" void kernel_launch(void* const* d_in, const int* in_sizes, int n_in,
                              void* d_out, int out_size, void* d_ws, size_t ws_size,
                              hipStream_t stream) {
    const float* x = (const float*)d_in[0];
    const float* k = (const float*)d_in[1];
    float* out = (float*)d_out;
    float* wt  = (float*)d_ws;   // 432 floats of transposed weights

    conv_weight_transpose<<<1, 512, 0, stream>>>(k, wt);

    // 2 w-halves * 2048 rows * 2 oc-halves = 8192 blocks of 256 threads
    conv2d_main<<<2 * CONV_H * 2, 256, 0, stream>>>(x, wt, out);
}

// Round 6
// 319.464 us; speedup vs baseline: 1.0715x; 1.0715x over previous
//
#include <hip/hip_runtime.h>

// Conv2d: x [3, 2048, 2048] f32, kernel [16, 3, 3, 3] f32, pad=1, stride=1,
// out [16, 2048, 2048] f32.
// Roofline: 268 MB write + 50 MB read ≈ 55 us @ ~6 TB/s. VALU fma floor 23 us.
// R2: back to read-x-once (16 oc/thread). ic-loop kept rolled (3-row window,
//     VGPR ~100 -> 5 waves/SIMD). Nontemporal stores (out is write-once; keep
//     L2 for x). XCD-bijective block swizzle (4096 % 8 == 0) for row locality.
// R4: fix compile error — __builtin_nontemporal_store needs a clang
//     ext_vector_type, not HIP's float4 class. No semantic change.
// R5: resubmit of R4 verbatim — R4 bench failed on GPU acquisition timeout.

#define CONV_H 2048
#define CONV_W 2048

typedef float f32x4 __attribute__((ext_vector_type(4)));

// [oc][ic][kh][kw] -> [tap][oc], tap = ic*9+kh*3+kw; 16 oc contiguous per tap
// so weight loads are wave-uniform s_load_dwordx16.
__global__ void conv_weight_transpose(const float* __restrict__ k,
                                      float* __restrict__ wt) {
    int t = threadIdx.x;
    if (t < 16 * 27) {
        int oc = t / 27;
        int r  = t % 27;
        wt[r * 16 + oc] = k[t];
    }
}

// b (after swizzle): bit0 = w-half, bits1..11 = h. Thread: float4 x 16 oc.
__global__ __launch_bounds__(256) void conv2d_main(const float* __restrict__ x,
                                                   const float* __restrict__ wt,
                                                   float* __restrict__ out) {
    // XCD swizzle: 4096 blocks / 8 XCDs -> 512 contiguous blocks per XCD.
    int b = (int)blockIdx.x;
    b = (b & 7) * 512 + (b >> 3);

    const int h  = b >> 1;                          // wave-uniform
    const int w0 = ((b & 1) * 256 + (int)threadIdx.x) << 2;

    float acc[16][4];
#pragma unroll
    for (int oc = 0; oc < 16; ++oc)
#pragma unroll
        for (int j = 0; j < 4; ++j) acc[oc][j] = 0.f;

#pragma unroll 1   // keep rolled: 3-row live window instead of 9 rows
    for (int ic = 0; ic < 3; ++ic) {
        const float* plane = x + (size_t)ic * (CONV_H * CONV_W);
        float in[3][6];
#pragma unroll
        for (int kh = 0; kh < 3; ++kh) {
            const int hy = h + kh - 1;              // wave-uniform branch
            if (hy >= 0 && hy < CONV_H) {
                const float* row = plane + (size_t)hy * CONV_W;
                const f32x4 c = *reinterpret_cast<const f32x4*>(row + w0);
                in[kh][0] = (w0 > 0) ? row[w0 - 1] : 0.f;
                in[kh][1] = c.x; in[kh][2] = c.y;
                in[kh][3] = c.z; in[kh][4] = c.w;
                in[kh][5] = (w0 + 4 < CONV_W) ? row[w0 + 4] : 0.f;
            } else {
#pragma unroll
                for (int j = 0; j < 6; ++j) in[kh][j] = 0.f;
            }
        }
#pragma unroll
        for (int kh = 0; kh < 3; ++kh) {
#pragma unroll
            for (int kw = 0; kw < 3; ++kw) {
                const float* wp = wt + ((ic * 3 + kh) * 3 + kw) * 16;
#pragma unroll
                for (int oc = 0; oc < 16; ++oc) {
                    const float wv = wp[oc];        // wave-uniform s_load
#pragma unroll
                    for (int j = 0; j < 4; ++j)
                        acc[oc][j] = fmaf(in[kh][kw + j], wv, acc[oc][j]);
                }
            }
        }
    }

    float* obase = out + (size_t)h * CONV_W + w0;
#pragma unroll
    for (int oc = 0; oc < 16; ++oc) {
        f32x4 v = { acc[oc][0], acc[oc][1], acc[oc][2], acc[oc][3] };
        __builtin_nontemporal_store(
            v, reinterpret_cast<f32x4*>(obase + (size_t)oc * (CONV_H * CONV_W)));
    }
}

extern "C" void kernel_launch(void* const* d_in, const int* in_sizes, int n_in,
                              void* d_out, int out_size, void* d_ws, size_t ws_size,
                              hipStream_t stream) {
    const float* x = (const float*)d_in[0];
    const float* k = (const float*)d_in[1];
    float* out = (float*)d_out;
    float* wt  = (float*)d_ws;   // 432 floats of transposed weights

    conv_weight_transpose<<<1, 512, 0, stream>>>(k, wt);

    // 2048 rows * 2 w-halves = 4096 blocks of 256 threads, x read exactly once.
    conv2d_main<<<4096, 256, 0, stream>>>(x, wt, out);
}